// Round 2
// baseline (398.583 us; speedup 1.0000x reference)
//
#include <hip/hip_runtime.h>

#define NN 2048
#define DD 256
#define HH 4
#define G3 768
#define ECAP 256

// ---------------------------------------------------------------------------
// Kernel A: all projections that depend only on x (fp32 in/out).
//   msg_l = x @ Wm_l^T + bm_l            [N, 256]  (l = 0,1)
//   acur_l = x @ Wa_l[:, :D]^T           [N, 4]
//   anb_l  = x @ Wa_l[:, D:]^T           [N, 4]
//   gh     = x @ whh^T + bhh             [N, 768]
// 8 rows per block; thread t owns output column t (and t+256, t+512 for gh).
// ---------------------------------------------------------------------------
__global__ __launch_bounds__(256) void proj_kernel(
    const float* __restrict__ x,
    const float* __restrict__ Wm0, const float* __restrict__ bm0, const float* __restrict__ Wa0,
    const float* __restrict__ Wm1, const float* __restrict__ bm1, const float* __restrict__ Wa1,
    const float* __restrict__ whh, const float* __restrict__ bhh,
    float* __restrict__ msg0, float* __restrict__ msg1,
    float* __restrict__ acur0, float* __restrict__ anb0,
    float* __restrict__ acur1, float* __restrict__ anb1,
    float* __restrict__ gh)
{
    __shared__ float xs[8][DD];
    const int t = threadIdx.x;
    const int r0 = blockIdx.x * 8;
    for (int r = 0; r < 8; ++r)
        xs[r][t] = x[(r0 + r) * DD + t];
    __syncthreads();

    float aM0[8] = {}, aM1[8] = {}, aG0[8] = {}, aG1[8] = {}, aG2[8] = {};
    const float4* wm0v = reinterpret_cast<const float4*>(Wm0 + (size_t)t * DD);
    const float4* wm1v = reinterpret_cast<const float4*>(Wm1 + (size_t)t * DD);
    const float4* g0v  = reinterpret_cast<const float4*>(whh + (size_t)t * DD);
    const float4* g1v  = reinterpret_cast<const float4*>(whh + (size_t)(t + 256) * DD);
    const float4* g2v  = reinterpret_cast<const float4*>(whh + (size_t)(t + 512) * DD);
    for (int kk = 0; kk < DD / 4; ++kk) {
        const float4 f0 = wm0v[kk], f1 = wm1v[kk];
        const float4 f2 = g0v[kk], f3 = g1v[kk], f4 = g2v[kk];
        const float w0a[4] = {f0.x, f0.y, f0.z, f0.w};
        const float w1a[4] = {f1.x, f1.y, f1.z, f1.w};
        const float w2a[4] = {f2.x, f2.y, f2.z, f2.w};
        const float w3a[4] = {f3.x, f3.y, f3.z, f3.w};
        const float w4a[4] = {f4.x, f4.y, f4.z, f4.w};
        #pragma unroll
        for (int u = 0; u < 4; ++u) {
            const int k = kk * 4 + u;
            #pragma unroll
            for (int r = 0; r < 8; ++r) {
                const float xv = xs[r][k];
                aM0[r] = fmaf(xv, w0a[u], aM0[r]);
                aM1[r] = fmaf(xv, w1a[u], aM1[r]);
                aG0[r] = fmaf(xv, w2a[u], aG0[r]);
                aG1[r] = fmaf(xv, w3a[u], aG1[r]);
                aG2[r] = fmaf(xv, w4a[u], aG2[r]);
            }
        }
    }
    const float b0 = bm0[t], b1 = bm1[t];
    const float bh0 = bhh[t], bh1 = bhh[t + 256], bh2 = bhh[t + 512];
    for (int r = 0; r < 8; ++r) {
        const int row = r0 + r;
        msg0[row * DD + t] = aM0[r] + b0;
        msg1[row * DD + t] = aM1[r] + b1;
        gh[row * G3 + t]       = aG0[r] + bh0;
        gh[row * G3 + t + 256] = aG1[r] + bh1;
        gh[row * G3 + t + 512] = aG2[r] + bh2;
    }
    // 16 tiny attention projections per row: threads 0..127 -> (row r, idx)
    if (t < 128) {
        const int r = t >> 4, idx = t & 15;
        const int h = idx & 3, which = idx >> 2;   // 0:acur0 1:anb0 2:acur1 3:anb1
        const float* Wa = (which < 2) ? Wa0 : Wa1;
        const int off = h * (2 * DD) + ((which & 1) ? DD : 0);
        float acc = 0.f;
        for (int k = 0; k < DD; ++k) acc = fmaf(xs[r][k], Wa[off + k], acc);
        float* dst = (which == 0) ? acur0 : (which == 1) ? anb0 : (which == 2) ? acur1 : anb1;
        dst[(r0 + r) * HH + h] = acc;
    }
}

// ---------------------------------------------------------------------------
// Kernel B: per target-node i (block), per layer (separate launch):
//  compact the ~31 in-edges (adj[j,i]!=0) into an LDS edge list with
//  precomputed scores, softmax over edges only (NEG entries underflow to 0
//  in fp32 exactly as in the reference), then aggregate msg rows.
//  Isolated nodes (ne==0) output exactly 0 (matches reference's *mask).
// ---------------------------------------------------------------------------
__global__ __launch_bounds__(256) void attn_kernel(
    const float* __restrict__ adj, const float* __restrict__ w, const float* __restrict__ ba,
    const float* __restrict__ acur, const float* __restrict__ anb,
    const float* __restrict__ msg, float* __restrict__ mout)
{
    const int i = blockIdx.x;
    const int t = threadIdx.x;
    __shared__ int ej[ECAP];
    __shared__ float es[HH][ECAP];
    __shared__ int cnt;
    if (t == 0) cnt = 0;
    __syncthreads();
    float ac[HH];
    #pragma unroll
    for (int h = 0; h < HH; ++h) ac[h] = acur[i * HH + h] + ba[h];
    const float4* anb4 = reinterpret_cast<const float4*>(anb);

    for (int j = t; j < NN; j += 256) {
        const float a = adj[(size_t)j * NN + i];
        if (a != 0.f) {
            const float wv = w[(size_t)j * NN + i];
            const int slot = atomicAdd(&cnt, 1);
            if (slot < ECAP) {
                ej[slot] = j;
                const float4 av = anb4[j];
                const float sv[4] = {av.x, av.y, av.z, av.w};
                #pragma unroll
                for (int h = 0; h < HH; ++h) {
                    float s = sv[h] + ac[h];
                    s = (s > 0.f) ? s : 0.2f * s;     // leaky_relu(0.2)
                    es[h][slot] = s * wv;             // edge-weight scaled score
                }
            }
        }
    }
    __syncthreads();
    const int ne = min(cnt, ECAP);
    if (t < HH) {
        float m = -1e30f;
        for (int e = 0; e < ne; ++e) m = fmaxf(m, es[t][e]);
        float l = 0.f;
        for (int e = 0; e < ne; ++e) l += expf(es[t][e] - m);
        const float inv = (l > 0.f) ? 1.f / l : 0.f;
        for (int e = 0; e < ne; ++e) es[t][e] = expf(es[t][e] - m) * inv;
    }
    __syncthreads();
    const int h = t >> 6;   // t = h*64 + d
    float acc = 0.f;
    for (int e = 0; e < ne; ++e)
        acc = fmaf(es[h][e], msg[(size_t)ej[e] * DD + t], acc);
    mout[(size_t)i * DD + t] = acc;   // agg[i, h, d] flattened
}

// ---------------------------------------------------------------------------
// Kernel C: GRU cell (torch semantics) + LayerNorm, 8 rows per block.
//   gi = [m0,m1] @ wih^T + bih ; gates; h ; LN(h)*g+b
// ---------------------------------------------------------------------------
__global__ __launch_bounds__(256) void gru_ln_kernel(
    const float* __restrict__ m0, const float* __restrict__ m1,
    const float* __restrict__ wih, const float* __restrict__ bih,
    const float* __restrict__ gh, const float* __restrict__ x,
    const float* __restrict__ ln_g, const float* __restrict__ ln_b,
    float* __restrict__ out)
{
    __shared__ float xs[8][2 * DD];
    __shared__ float rs1[4], rs2[4];
    const int t = threadIdx.x;
    const int r0 = blockIdx.x * 8;
    for (int r = 0; r < 8; ++r) {
        xs[r][t]       = m0[(r0 + r) * DD + t];
        xs[r][t + 256] = m1[(r0 + r) * DD + t];
    }
    __syncthreads();
    float aR[8] = {}, aZ[8] = {}, aN[8] = {};
    const float4* wrv = reinterpret_cast<const float4*>(wih + (size_t)t * 512);
    const float4* wzv = reinterpret_cast<const float4*>(wih + (size_t)(t + 256) * 512);
    const float4* wnv = reinterpret_cast<const float4*>(wih + (size_t)(t + 512) * 512);
    for (int kk = 0; kk < 512 / 4; ++kk) {
        const float4 fr = wrv[kk], fz = wzv[kk], fn = wnv[kk];
        const float ra[4] = {fr.x, fr.y, fr.z, fr.w};
        const float za[4] = {fz.x, fz.y, fz.z, fz.w};
        const float na[4] = {fn.x, fn.y, fn.z, fn.w};
        #pragma unroll
        for (int u = 0; u < 4; ++u) {
            const int k = kk * 4 + u;
            #pragma unroll
            for (int r = 0; r < 8; ++r) {
                const float xv = xs[r][k];
                aR[r] = fmaf(xv, ra[u], aR[r]);
                aZ[r] = fmaf(xv, za[u], aZ[r]);
                aN[r] = fmaf(xv, na[u], aN[r]);
            }
        }
    }
    const float br = bih[t], bz = bih[t + 256], bn = bih[t + 512];
    const float gv = ln_g[t], bv = ln_b[t];
    float hv[8];
    #pragma unroll
    for (int r = 0; r < 8; ++r) {
        const int row = r0 + r;
        const float ghr = gh[row * G3 + t];
        const float ghz = gh[row * G3 + t + 256];
        const float ghn = gh[row * G3 + t + 512];
        const float rr = 1.f / (1.f + expf(-(aR[r] + br + ghr)));
        const float zz = 1.f / (1.f + expf(-(aZ[r] + bz + ghz)));
        const float nn = tanhf(aN[r] + bn + rr * ghn);
        hv[r] = (1.f - zz) * nn + zz * x[row * DD + t];
    }
    const int lane = t & 63, wid = t >> 6;
    for (int r = 0; r < 8; ++r) {
        float s1 = hv[r], s2 = hv[r] * hv[r];
        #pragma unroll
        for (int off = 32; off; off >>= 1) {
            s1 += __shfl_down(s1, off);
            s2 += __shfl_down(s2, off);
        }
        if (lane == 0) { rs1[wid] = s1; rs2[wid] = s2; }
        __syncthreads();
        const float sum = rs1[0] + rs1[1] + rs1[2] + rs1[3];
        const float sq  = rs2[0] + rs2[1] + rs2[2] + rs2[3];
        const float mu  = sum * (1.f / DD);
        const float var = sq * (1.f / DD) - mu * mu;
        const float inv = rsqrtf(var + 1e-5f);
        out[(r0 + r) * DD + t] = (hv[r] - mu) * inv * gv + bv;
        __syncthreads();
    }
}

extern "C" void kernel_launch(void* const* d_in, const int* in_sizes, int n_in,
                              void* d_out, int out_size, void* d_ws, size_t ws_size,
                              hipStream_t stream)
{
    const float* x    = (const float*)d_in[0];
    const float* adj0 = (const float*)d_in[1];
    const float* adj1 = (const float*)d_in[2];
    const float* w0   = (const float*)d_in[3];
    const float* w1   = (const float*)d_in[4];
    const float* Wm0  = (const float*)d_in[5];
    const float* bm0  = (const float*)d_in[6];
    const float* Wa0  = (const float*)d_in[7];
    const float* ba0  = (const float*)d_in[8];
    const float* Wm1  = (const float*)d_in[9];
    const float* bm1  = (const float*)d_in[10];
    const float* Wa1  = (const float*)d_in[11];
    const float* ba1  = (const float*)d_in[12];
    const float* wih  = (const float*)d_in[13];
    const float* whh  = (const float*)d_in[14];
    const float* bih  = (const float*)d_in[15];
    const float* bhh  = (const float*)d_in[16];
    const float* lng  = (const float*)d_in[17];
    const float* lnb  = (const float*)d_in[18];
    float* out = (float*)d_out;

    float* ws = (float*)d_ws;
    float* msg0  = ws;  ws += NN * DD;
    float* msg1  = ws;  ws += NN * DD;
    float* acur0 = ws;  ws += NN * HH;
    float* anb0  = ws;  ws += NN * HH;
    float* acur1 = ws;  ws += NN * HH;
    float* anb1  = ws;  ws += NN * HH;
    float* gh    = ws;  ws += NN * G3;
    float* m0    = ws;  ws += NN * DD;
    float* m1    = ws;  ws += NN * DD;
    // total ws use: ~14.8 MB of fp32

    proj_kernel<<<NN / 8, 256, 0, stream>>>(x, Wm0, bm0, Wa0, Wm1, bm1, Wa1, whh, bhh,
                                            msg0, msg1, acur0, anb0, acur1, anb1, gh);
    attn_kernel<<<NN, 256, 0, stream>>>(adj0, w0, ba0, acur0, anb0, msg0, m0);
    attn_kernel<<<NN, 256, 0, stream>>>(adj1, w1, ba1, acur1, anb1, msg1, m1);
    gru_ln_kernel<<<NN / 8, 256, 0, stream>>>(m0, m1, wih, bih, gh, x, lng, lnb, out);
}

// Round 3
// 264.165 us; speedup vs baseline: 1.5088x; 1.5088x over previous
//
#include <hip/hip_runtime.h>

#define NN 2048
#define DD 256
#define HH 4
#define PW 1280      // packed proj output width: 256 msg0 | 256 msg1 | 768 gh
#define ECAP 128

// ---------------------------------------------------------------------------
// pack: Wcat[1280][256] = [Wm0; Wm1; whh] row-concat; bcat = [bm0; bm1; bhh];
//       zero edge counters. Runs once per launch (ws is re-poisoned each call).
// ---------------------------------------------------------------------------
__global__ __launch_bounds__(256) void pack_kernel(
    const float* __restrict__ Wm0, const float* __restrict__ Wm1, const float* __restrict__ whh,
    const float* __restrict__ bm0, const float* __restrict__ bm1, const float* __restrict__ bhh,
    float* __restrict__ Wcat, float* __restrict__ bcat, int* __restrict__ cnt)
{
    const int b = blockIdx.x, t = threadIdx.x;
    if (b < 320) {
        const int c = b * 4 + (t >> 6);
        const int k4 = (t & 63) * 4;
        const float* src = (c < 256) ? Wm0 + (size_t)c * DD
                         : (c < 512) ? Wm1 + (size_t)(c - 256) * DD
                                     : whh + (size_t)(c - 512) * DD;
        *(float4*)(Wcat + (size_t)c * DD + k4) = *(const float4*)(src + k4);
    } else {
        const int z = (b - 320) * 256 + t;      // 0..4095
        cnt[z] = 0;
        if (z < PW)
            bcat[z] = (z < 256) ? bm0[z] : (z < 512) ? bm1[z - 256] : bhh[z - 512];
    }
}

// ---------------------------------------------------------------------------
// gemm64: C[M,N] = A[M,K] @ B[N,K]^T + bias.  64x64 tile, 4x4 per thread,
// K staged in LDS in transposed layout so fragments are ds_read_b128.
// ---------------------------------------------------------------------------
__global__ __launch_bounds__(256) void gemm64(
    const float* __restrict__ A, const float* __restrict__ B, const float* __restrict__ bias,
    float* __restrict__ C, int lda, int ldb, int ldc, int K)
{
    __shared__ float as[64][68];
    __shared__ float bs[64][68];
    const int t = threadIdx.x;
    const int tx = t & 15, ty = t >> 4;
    const int r0 = blockIdx.y * 64, c0 = blockIdx.x * 64;
    float acc[4][4] = {};

    for (int k0 = 0; k0 < K; k0 += 64) {
        #pragma unroll
        for (int w = 0; w < 4; ++w) {
            const int row = w * 16 + ty;
            const int k4 = tx * 4;
            const float4 av = *(const float4*)(A + (size_t)(r0 + row) * lda + k0 + k4);
            as[k4 + 0][row] = av.x; as[k4 + 1][row] = av.y;
            as[k4 + 2][row] = av.z; as[k4 + 3][row] = av.w;
            const float4 bv = *(const float4*)(B + (size_t)(c0 + row) * ldb + k0 + k4);
            bs[k4 + 0][row] = bv.x; bs[k4 + 1][row] = bv.y;
            bs[k4 + 2][row] = bv.z; bs[k4 + 3][row] = bv.w;
        }
        __syncthreads();
        #pragma unroll 8
        for (int k = 0; k < 64; ++k) {
            const float4 a = *(const float4*)&as[k][ty * 4];
            const float4 b = *(const float4*)&bs[k][tx * 4];
            const float aa[4] = {a.x, a.y, a.z, a.w};
            const float bb[4] = {b.x, b.y, b.z, b.w};
            #pragma unroll
            for (int ri = 0; ri < 4; ++ri)
                #pragma unroll
                for (int ci = 0; ci < 4; ++ci)
                    acc[ri][ci] = fmaf(aa[ri], bb[ci], acc[ri][ci]);
        }
        __syncthreads();
    }
    const float4 bv = *(const float4*)(bias + c0 + tx * 4);
    const float bb[4] = {bv.x, bv.y, bv.z, bv.w};
    #pragma unroll
    for (int ri = 0; ri < 4; ++ri) {
        float4 o;
        o.x = acc[ri][0] + bb[0]; o.y = acc[ri][1] + bb[1];
        o.z = acc[ri][2] + bb[2]; o.w = acc[ri][3] + bb[3];
        *(float4*)(C + (size_t)(r0 + ty * 4 + ri) * ldc + c0 + tx * 4) = o;
    }
}

// ---------------------------------------------------------------------------
// attn_proj: acur/anb[l][i][h] = x[i] . Wa_l[h, half]  (16 dots per row)
// ---------------------------------------------------------------------------
__global__ __launch_bounds__(256) void attn_proj(
    const float* __restrict__ x, const float* __restrict__ Wa0, const float* __restrict__ Wa1,
    float* __restrict__ acur, float* __restrict__ anb)
{
    __shared__ float xs[16][257];
    const int t = threadIdx.x;
    const int i0 = blockIdx.x * 16;
    for (int rr = 0; rr < 16; ++rr)
        xs[rr][t] = x[(size_t)(i0 + rr) * DD + t];
    __syncthreads();
    const int r = t >> 4, idx = t & 15;
    const int l = idx >> 3, isnb = (idx >> 2) & 1, h = idx & 3;
    const float* wrow = (l ? Wa1 : Wa0) + h * (2 * DD) + isnb * DD;
    float acc = 0.f;
    for (int k = 0; k < DD; ++k) acc = fmaf(xs[r][k], wrow[k], acc);
    float* dst = isnb ? anb : acur;
    dst[((size_t)l * NN + i0 + r) * HH + h] = acc;
}

// ---------------------------------------------------------------------------
// edge_build: coalesced scan of adj rows; scatter (j, w) into per-column
// edge lists via atomic counters. ~31 edges/column, ECAP=128 is +17 sigma.
// ---------------------------------------------------------------------------
__global__ __launch_bounds__(256) void edge_build(
    const float* __restrict__ adj0, const float* __restrict__ adj1,
    const float* __restrict__ w0, const float* __restrict__ w1,
    int* __restrict__ cnt, int* __restrict__ ej, float* __restrict__ ew)
{
    const int j = blockIdx.x, l = blockIdx.y, t = threadIdx.x;
    const float* adj = l ? adj1 : adj0;
    const float* w   = l ? w1 : w0;
    #pragma unroll
    for (int it = 0; it < 2; ++it) {
        const int i4 = (t + it * 256) * 4;
        const float4 a = *(const float4*)(adj + (size_t)j * NN + i4);
        const float av[4] = {a.x, a.y, a.z, a.w};
        #pragma unroll
        for (int u = 0; u < 4; ++u) {
            if (av[u] != 0.f) {
                const int i = i4 + u;
                const int slot = atomicAdd(&cnt[l * NN + i], 1);
                if (slot < ECAP) {
                    const size_t base = ((size_t)l * NN + i) * ECAP + slot;
                    ej[base] = j;
                    ew[base] = w[(size_t)j * NN + i];
                }
            }
        }
    }
}

// ---------------------------------------------------------------------------
// attn: per (node i, layer l): edge-only softmax (exactly equals the dense
// reference: exp(NEG - m) underflows to 0; isolated nodes -> 0), then
// aggregate msg rows (P cols l*256..l*256+255) into mcat.
// ---------------------------------------------------------------------------
__global__ __launch_bounds__(256) void attn_kernel(
    const int* __restrict__ cnt, const int* __restrict__ ej, const float* __restrict__ ew,
    const float* __restrict__ acur, const float* __restrict__ anb,
    const float* __restrict__ ba0, const float* __restrict__ ba1,
    const float* __restrict__ P, float* __restrict__ mcat)
{
    const int i = blockIdx.x, l = blockIdx.y, t = threadIdx.x;
    __shared__ float es[HH][ECAP];
    __shared__ int ejs[ECAP];
    const int ne = min(cnt[l * NN + i], ECAP);
    const float* ba = l ? ba1 : ba0;
    float ac[HH];
    #pragma unroll
    for (int h = 0; h < HH; ++h) ac[h] = acur[((size_t)l * NN + i) * HH + h] + ba[h];
    const size_t ebase = ((size_t)l * NN + i) * ECAP;
    for (int e = t; e < ne; e += 256) {
        const int j = ej[ebase + e];
        const float wv = ew[ebase + e];
        ejs[e] = j;
        const float4 av = *(const float4*)(anb + ((size_t)l * NN + j) * HH);
        const float sv[4] = {av.x, av.y, av.z, av.w};
        #pragma unroll
        for (int h = 0; h < HH; ++h) {
            float s = sv[h] + ac[h];
            s = (s > 0.f) ? s : 0.2f * s;           // leaky_relu(0.2)
            es[h][e] = s * wv;
        }
    }
    __syncthreads();
    if (t < HH) {
        float m = -1e30f;
        for (int e = 0; e < ne; ++e) m = fmaxf(m, es[t][e]);
        float lsum = 0.f;
        for (int e = 0; e < ne; ++e) lsum += expf(es[t][e] - m);
        const float inv = (lsum > 0.f) ? 1.f / lsum : 0.f;
        for (int e = 0; e < ne; ++e) es[t][e] = expf(es[t][e] - m) * inv;
    }
    __syncthreads();
    const int h = t >> 6;
    float acc = 0.f;
    for (int e = 0; e < ne; ++e)
        acc = fmaf(es[h][e], P[(size_t)ejs[e] * PW + l * DD + t], acc);
    mcat[(size_t)i * (2 * DD) + l * DD + t] = acc;
}

// ---------------------------------------------------------------------------
// gates_ln: GRU gates (gi already includes bih via gemm bias) + LayerNorm.
// ---------------------------------------------------------------------------
__global__ __launch_bounds__(256) void gates_ln(
    const float* __restrict__ gi, const float* __restrict__ P, const float* __restrict__ x,
    const float* __restrict__ lng, const float* __restrict__ lnb, float* __restrict__ out)
{
    __shared__ float rs1[4], rs2[4];
    const int t = threadIdx.x;
    const int r0 = blockIdx.x * 4;
    const float gv = lng[t], bv = lnb[t];
    float hv[4];
    #pragma unroll
    for (int r = 0; r < 4; ++r) {
        const int row = r0 + r;
        const float gir = gi[(size_t)row * 768 + t];
        const float giz = gi[(size_t)row * 768 + 256 + t];
        const float gin = gi[(size_t)row * 768 + 512 + t];
        const float ghr = P[(size_t)row * PW + 512 + t];
        const float ghz = P[(size_t)row * PW + 768 + t];
        const float ghn = P[(size_t)row * PW + 1024 + t];
        const float rr = 1.f / (1.f + expf(-(gir + ghr)));
        const float zz = 1.f / (1.f + expf(-(giz + ghz)));
        const float nn = tanhf(gin + rr * ghn);
        hv[r] = (1.f - zz) * nn + zz * x[(size_t)row * DD + t];
    }
    const int lane = t & 63, wid = t >> 6;
    for (int r = 0; r < 4; ++r) {
        float s1 = hv[r], s2 = hv[r] * hv[r];
        #pragma unroll
        for (int off = 32; off; off >>= 1) {
            s1 += __shfl_down(s1, off);
            s2 += __shfl_down(s2, off);
        }
        if (lane == 0) { rs1[wid] = s1; rs2[wid] = s2; }
        __syncthreads();
        const float sum = rs1[0] + rs1[1] + rs1[2] + rs1[3];
        const float sq  = rs2[0] + rs2[1] + rs2[2] + rs2[3];
        const float mu  = sum * (1.f / DD);
        const float var = sq * (1.f / DD) - mu * mu;
        const float inv = rsqrtf(var + 1e-5f);
        out[(size_t)(r0 + r) * DD + t] = (hv[r] - mu) * inv * gv + bv;
        __syncthreads();
    }
}

extern "C" void kernel_launch(void* const* d_in, const int* in_sizes, int n_in,
                              void* d_out, int out_size, void* d_ws, size_t ws_size,
                              hipStream_t stream)
{
    const float* x    = (const float*)d_in[0];
    const float* adj0 = (const float*)d_in[1];
    const float* adj1 = (const float*)d_in[2];
    const float* w0   = (const float*)d_in[3];
    const float* w1   = (const float*)d_in[4];
    const float* Wm0  = (const float*)d_in[5];
    const float* bm0  = (const float*)d_in[6];
    const float* Wa0  = (const float*)d_in[7];
    const float* ba0  = (const float*)d_in[8];
    const float* Wm1  = (const float*)d_in[9];
    const float* bm1  = (const float*)d_in[10];
    const float* Wa1  = (const float*)d_in[11];
    const float* ba1  = (const float*)d_in[12];
    const float* wih  = (const float*)d_in[13];
    const float* whh  = (const float*)d_in[14];
    const float* bih  = (const float*)d_in[15];
    const float* bhh  = (const float*)d_in[16];
    const float* lng  = (const float*)d_in[17];
    const float* lnb  = (const float*)d_in[18];
    float* out = (float*)d_out;

    float* ws = (float*)d_ws;
    float* Wcat = ws;            ws += PW * DD;          // 1280x256
    float* bcat = ws;            ws += PW;
    float* P    = ws;            ws += (size_t)NN * PW;  // 2048x1280
    float* acur = ws;            ws += 2 * NN * HH;
    float* anb  = ws;            ws += 2 * NN * HH;
    int*   cnt  = (int*)ws;      ws += 2 * NN;
    int*   ej   = (int*)ws;      ws += 2 * NN * ECAP;
    float* ew   = ws;            ws += 2 * NN * ECAP;
    float* mcat = ws;            ws += (size_t)NN * 2 * DD;  // 2048x512
    float* gi   = ws;            ws += (size_t)NN * 768;     // 2048x768
    // total ~26.6 MB of fp32 workspace

    pack_kernel<<<336, 256, 0, stream>>>(Wm0, Wm1, whh, bm0, bm1, bhh, Wcat, bcat, cnt);
    gemm64<<<dim3(PW / 64, NN / 64), 256, 0, stream>>>(x, Wcat, bcat, P, DD, DD, PW, DD);
    attn_proj<<<NN / 16, 256, 0, stream>>>(x, Wa0, Wa1, acur, anb);
    edge_build<<<dim3(NN, 2), 256, 0, stream>>>(adj0, adj1, w0, w1, cnt, ej, ew);
    attn_kernel<<<dim3(NN, 2), 256, 0, stream>>>(cnt, ej, ew, acur, anb, ba0, ba1, P, mcat);
    gemm64<<<dim3(768 / 64, NN / 64), 256, 0, stream>>>(mcat, wih, bih, gi, 2 * DD, 2 * DD, 768, 2 * DD);
    gates_ln<<<NN / 4, 256, 0, stream>>>(gi, P, x, lng, lnb, out);
}

// Round 4
// 216.566 us; speedup vs baseline: 1.8405x; 1.2198x over previous
//
#include <hip/hip_runtime.h>

#define NN 2048
#define DD 256
#define HH 4
#define PW 1280      // packed proj output width: 256 msg0 | 256 msg1 | 768 gh
#define ECAP 128

typedef unsigned short ushort_t;
typedef __attribute__((ext_vector_type(8))) short s8;
typedef __attribute__((ext_vector_type(4))) float f4;

__device__ __forceinline__ ushort_t f2b(float f) {   // fp32 -> bf16 bits, RNE
    unsigned int u = __float_as_uint(f);
    return (ushort_t)((u + 0x7fffu + ((u >> 16) & 1u)) >> 16);
}

// ---------------------------------------------------------------------------
// convert: xb = bf16(x); Wcatb = bf16([Wm0;Wm1;whh]); wihb = bf16(wih);
//          bcat = [bm0;bm1;bhh] fp32; cnt = 0.   One elem per thread.
// ---------------------------------------------------------------------------
__global__ __launch_bounds__(256) void convert_kernel(
    const float* __restrict__ x, const float* __restrict__ Wm0, const float* __restrict__ Wm1,
    const float* __restrict__ whh, const float* __restrict__ wih,
    const float* __restrict__ bm0, const float* __restrict__ bm1, const float* __restrict__ bhh,
    ushort_t* __restrict__ xb, ushort_t* __restrict__ Wcatb, ushort_t* __restrict__ wihb,
    float* __restrict__ bcat, int* __restrict__ cnt)
{
    int id = blockIdx.x * 256 + threadIdx.x;
    if (id < NN * DD) { xb[id] = f2b(x[id]); return; }
    id -= NN * DD;
    if (id < PW * DD) {
        const int c = id >> 8, k = id & 255;
        const float v = (c < 256) ? Wm0[c * DD + k]
                      : (c < 512) ? Wm1[(c - 256) * DD + k]
                                  : whh[(c - 512) * DD + k];
        Wcatb[id] = f2b(v); return;
    }
    id -= PW * DD;
    if (id < 768 * 512) { wihb[id] = f2b(wih[id]); return; }
    id -= 768 * 512;
    if (id < PW) {
        bcat[id] = (id < 256) ? bm0[id] : (id < 512) ? bm1[id - 256] : bhh[id - 512];
        return;
    }
    id -= PW;
    if (id < 2 * NN) cnt[id] = 0;
}

// ---------------------------------------------------------------------------
// gemm_mfma: C[M,N] = A[M,K] @ B[N,K]^T + bias.  A,B bf16 (K-contiguous),
// C fp32. 64x64 block tile, 4 waves * (32x32 via 2x2 mfma_f32_16x16x32_bf16).
// LDS [64][72] ushort: row stride 36 dwords -> frag ds_read_b128 and staging
// stores both land 8 lanes / 4-bank group = conflict-free minimum.
// ---------------------------------------------------------------------------
__global__ __launch_bounds__(256) void gemm_mfma(
    const ushort_t* __restrict__ A, const ushort_t* __restrict__ B,
    const float* __restrict__ bias, float* __restrict__ C,
    int lda, int ldb, int ldc, int K)
{
    __shared__ ushort_t as[64][72];
    __shared__ ushort_t bs[64][72];
    const int t = threadIdx.x;
    const int wave = t >> 6, lane = t & 63;
    const int r0 = blockIdx.y * 64, c0 = blockIdx.x * 64;
    const int wm = (wave & 1) * 32, wn = (wave >> 1) * 32;
    const int fm = lane & 15, fq = lane >> 4;     // fragment row/col, k-quad

    f4 acc[2][2] = {};

    for (int k0 = 0; k0 < K; k0 += 64) {
        #pragma unroll
        for (int it = 0; it < 2; ++it) {
            const int q = t + it * 256;           // chunk id 0..511
            const int m = q >> 3, c = q & 7;      // row, 16B-chunk within row
            *(uint4*)&as[m][c * 8] = *(const uint4*)(A + (size_t)(r0 + m) * lda + k0 + c * 8);
            *(uint4*)&bs[m][c * 8] = *(const uint4*)(B + (size_t)(c0 + m) * ldb + k0 + c * 8);
        }
        __syncthreads();
        #pragma unroll
        for (int kk = 0; kk < 2; ++kk) {
            const int kb = kk * 32 + fq * 8;
            const s8 a0 = *(const s8*)&as[wm + fm][kb];
            const s8 a1 = *(const s8*)&as[wm + 16 + fm][kb];
            const s8 b0 = *(const s8*)&bs[wn + fm][kb];
            const s8 b1 = *(const s8*)&bs[wn + 16 + fm][kb];
            acc[0][0] = __builtin_amdgcn_mfma_f32_16x16x32_bf16(a0, b0, acc[0][0], 0, 0, 0);
            acc[0][1] = __builtin_amdgcn_mfma_f32_16x16x32_bf16(a0, b1, acc[0][1], 0, 0, 0);
            acc[1][0] = __builtin_amdgcn_mfma_f32_16x16x32_bf16(a1, b0, acc[1][0], 0, 0, 0);
            acc[1][1] = __builtin_amdgcn_mfma_f32_16x16x32_bf16(a1, b1, acc[1][1], 0, 0, 0);
        }
        __syncthreads();
    }
    // C/D layout (m89-verified): col = lane&15, row = (lane>>4)*4 + reg
    #pragma unroll
    for (int ni = 0; ni < 2; ++ni) {
        const int col = c0 + wn + ni * 16 + fm;
        const float bv = bias[col];
        #pragma unroll
        for (int mi = 0; mi < 2; ++mi) {
            #pragma unroll
            for (int r = 0; r < 4; ++r) {
                C[(size_t)(r0 + wm + mi * 16 + fq * 4 + r) * ldc + col] = acc[mi][ni][r] + bv;
            }
        }
    }
}

// ---------------------------------------------------------------------------
// attn_proj: acur/anb[l][i][h] = x[i] . Wa_l[h, half]  (fp32, exact)
// ---------------------------------------------------------------------------
__global__ __launch_bounds__(256) void attn_proj(
    const float* __restrict__ x, const float* __restrict__ Wa0, const float* __restrict__ Wa1,
    float* __restrict__ acur, float* __restrict__ anb)
{
    __shared__ float xs[16][257];
    const int t = threadIdx.x;
    const int i0 = blockIdx.x * 16;
    for (int rr = 0; rr < 16; ++rr)
        xs[rr][t] = x[(size_t)(i0 + rr) * DD + t];
    __syncthreads();
    const int r = t >> 4, idx = t & 15;
    const int l = idx >> 3, isnb = (idx >> 2) & 1, h = idx & 3;
    const float* wrow = (l ? Wa1 : Wa0) + h * (2 * DD) + isnb * DD;
    float acc = 0.f;
    for (int k = 0; k < DD; ++k) acc = fmaf(xs[r][k], wrow[k], acc);
    float* dst = isnb ? anb : acur;
    dst[((size_t)l * NN + i0 + r) * HH + h] = acc;
}

// ---------------------------------------------------------------------------
// edge_build: coalesced scan of adj rows; scatter (j, w) into per-column lists.
// ---------------------------------------------------------------------------
__global__ __launch_bounds__(256) void edge_build(
    const float* __restrict__ adj0, const float* __restrict__ adj1,
    const float* __restrict__ w0, const float* __restrict__ w1,
    int* __restrict__ cnt, int* __restrict__ ej, float* __restrict__ ew)
{
    const int j = blockIdx.x, l = blockIdx.y, t = threadIdx.x;
    const float* adj = l ? adj1 : adj0;
    const float* w   = l ? w1 : w0;
    #pragma unroll
    for (int it = 0; it < 2; ++it) {
        const int i4 = (t + it * 256) * 4;
        const float4 a = *(const float4*)(adj + (size_t)j * NN + i4);
        const float av[4] = {a.x, a.y, a.z, a.w};
        #pragma unroll
        for (int u = 0; u < 4; ++u) {
            if (av[u] != 0.f) {
                const int i = i4 + u;
                const int slot = atomicAdd(&cnt[l * NN + i], 1);
                if (slot < ECAP) {
                    const size_t base = ((size_t)l * NN + i) * ECAP + slot;
                    ej[base] = j;
                    ew[base] = w[(size_t)j * NN + i];
                }
            }
        }
    }
}

// ---------------------------------------------------------------------------
// attn: edge-only softmax (== dense reference: exp(NEG-m) underflows to 0;
// isolated nodes -> 0) + aggregation of P msg columns. mcat written as bf16
// (it is the A operand of the second MFMA gemm).
// ---------------------------------------------------------------------------
__global__ __launch_bounds__(256) void attn_kernel(
    const int* __restrict__ cnt, const int* __restrict__ ej, const float* __restrict__ ew,
    const float* __restrict__ acur, const float* __restrict__ anb,
    const float* __restrict__ ba0, const float* __restrict__ ba1,
    const float* __restrict__ P, ushort_t* __restrict__ mcatb)
{
    const int i = blockIdx.x, l = blockIdx.y, t = threadIdx.x;
    __shared__ float es[HH][ECAP];
    __shared__ int ejs[ECAP];
    const int ne = min(cnt[l * NN + i], ECAP);
    const float* ba = l ? ba1 : ba0;
    float ac[HH];
    #pragma unroll
    for (int h = 0; h < HH; ++h) ac[h] = acur[((size_t)l * NN + i) * HH + h] + ba[h];
    const size_t ebase = ((size_t)l * NN + i) * ECAP;
    for (int e = t; e < ne; e += 256) {
        const int j = ej[ebase + e];
        const float wv = ew[ebase + e];
        ejs[e] = j;
        const float4 av = *(const float4*)(anb + ((size_t)l * NN + j) * HH);
        const float sv[4] = {av.x, av.y, av.z, av.w};
        #pragma unroll
        for (int h = 0; h < HH; ++h) {
            float s = sv[h] + ac[h];
            s = (s > 0.f) ? s : 0.2f * s;           // leaky_relu(0.2)
            es[h][e] = s * wv;
        }
    }
    __syncthreads();
    if (t < HH) {
        float m = -1e30f;
        for (int e = 0; e < ne; ++e) m = fmaxf(m, es[t][e]);
        float lsum = 0.f;
        for (int e = 0; e < ne; ++e) lsum += expf(es[t][e] - m);
        const float inv = (lsum > 0.f) ? 1.f / lsum : 0.f;
        for (int e = 0; e < ne; ++e) es[t][e] = expf(es[t][e] - m) * inv;
    }
    __syncthreads();
    const int h = t >> 6;
    float acc = 0.f;
    for (int e = 0; e < ne; ++e)
        acc = fmaf(es[h][e], P[(size_t)ejs[e] * PW + l * DD + t], acc);
    mcatb[(size_t)i * (2 * DD) + l * DD + t] = f2b(acc);
}

// ---------------------------------------------------------------------------
// gates_ln: GRU gates (gi includes bih via gemm bias; gh lives in P) + LN.
// ---------------------------------------------------------------------------
__global__ __launch_bounds__(256) void gates_ln(
    const float* __restrict__ gi, const float* __restrict__ P, const float* __restrict__ x,
    const float* __restrict__ lng, const float* __restrict__ lnb, float* __restrict__ out)
{
    __shared__ float rs1[4], rs2[4];
    const int t = threadIdx.x;
    const int r0 = blockIdx.x * 4;
    const float gv = lng[t], bv = lnb[t];
    float hv[4];
    #pragma unroll
    for (int r = 0; r < 4; ++r) {
        const int row = r0 + r;
        const float gir = gi[(size_t)row * 768 + t];
        const float giz = gi[(size_t)row * 768 + 256 + t];
        const float gin = gi[(size_t)row * 768 + 512 + t];
        const float ghr = P[(size_t)row * PW + 512 + t];
        const float ghz = P[(size_t)row * PW + 768 + t];
        const float ghn = P[(size_t)row * PW + 1024 + t];
        const float rr = 1.f / (1.f + expf(-(gir + ghr)));
        const float zz = 1.f / (1.f + expf(-(giz + ghz)));
        const float nn = tanhf(gin + rr * ghn);
        hv[r] = (1.f - zz) * nn + zz * x[(size_t)row * DD + t];
    }
    const int lane = t & 63, wid = t >> 6;
    for (int r = 0; r < 4; ++r) {
        float s1 = hv[r], s2 = hv[r] * hv[r];
        #pragma unroll
        for (int off = 32; off; off >>= 1) {
            s1 += __shfl_down(s1, off);
            s2 += __shfl_down(s2, off);
        }
        if (lane == 0) { rs1[wid] = s1; rs2[wid] = s2; }
        __syncthreads();
        const float sum = rs1[0] + rs1[1] + rs1[2] + rs1[3];
        const float sq  = rs2[0] + rs2[1] + rs2[2] + rs2[3];
        const float mu  = sum * (1.f / DD);
        const float var = sq * (1.f / DD) - mu * mu;
        const float inv = rsqrtf(var + 1e-5f);
        out[(size_t)(r0 + r) * DD + t] = (hv[r] - mu) * inv * gv + bv;
        __syncthreads();
    }
}

extern "C" void kernel_launch(void* const* d_in, const int* in_sizes, int n_in,
                              void* d_out, int out_size, void* d_ws, size_t ws_size,
                              hipStream_t stream)
{
    const float* x    = (const float*)d_in[0];
    const float* adj0 = (const float*)d_in[1];
    const float* adj1 = (const float*)d_in[2];
    const float* w0   = (const float*)d_in[3];
    const float* w1   = (const float*)d_in[4];
    const float* Wm0  = (const float*)d_in[5];
    const float* bm0  = (const float*)d_in[6];
    const float* Wa0  = (const float*)d_in[7];
    const float* ba0  = (const float*)d_in[8];
    const float* Wm1  = (const float*)d_in[9];
    const float* bm1  = (const float*)d_in[10];
    const float* Wa1  = (const float*)d_in[11];
    const float* ba1  = (const float*)d_in[12];
    const float* wih  = (const float*)d_in[13];
    const float* whh  = (const float*)d_in[14];
    const float* bih  = (const float*)d_in[15];
    const float* bhh  = (const float*)d_in[16];
    const float* lng  = (const float*)d_in[17];
    const float* lnb  = (const float*)d_in[18];
    float* out = (float*)d_out;

    float* ws = (float*)d_ws;
    float* P    = ws;            ws += (size_t)NN * PW;   // 2048x1280 fp32
    float* bcat = ws;            ws += PW;
    float* acur = ws;            ws += 2 * NN * HH;
    float* anb  = ws;            ws += 2 * NN * HH;
    int*   cnt  = (int*)ws;      ws += 2 * NN;
    int*   ej   = (int*)ws;      ws += 2 * NN * ECAP;
    float* ew   = ws;            ws += 2 * NN * ECAP;
    float* gi   = ws;            ws += (size_t)NN * 768;  // fp32
    ushort_t* xb    = (ushort_t*)ws;  ws += (size_t)NN * DD / 2;
    ushort_t* Wcatb = (ushort_t*)ws;  ws += (size_t)PW * DD / 2;
    ushort_t* wihb  = (ushort_t*)ws;  ws += (size_t)768 * 512 / 2;
    ushort_t* mcatb = (ushort_t*)ws;  ws += (size_t)NN * 512 / 2;
    // total ~25.7 MB

    const int conv_elems = NN * DD + PW * DD + 768 * 512 + PW + 2 * NN;
    convert_kernel<<<(conv_elems + 255) / 256, 256, 0, stream>>>(
        x, Wm0, Wm1, whh, wih, bm0, bm1, bhh, xb, Wcatb, wihb, bcat, cnt);
    gemm_mfma<<<dim3(PW / 64, NN / 64), 256, 0, stream>>>(xb, Wcatb, bcat, P, DD, DD, PW, DD);
    attn_proj<<<NN / 16, 256, 0, stream>>>(x, Wa0, Wa1, acur, anb);
    edge_build<<<dim3(NN, 2), 256, 0, stream>>>(adj0, adj1, w0, w1, cnt, ej, ew);
    attn_kernel<<<dim3(NN, 2), 256, 0, stream>>>(cnt, ej, ew, acur, anb, ba0, ba1, P, mcatb);
    gemm_mfma<<<dim3(768 / 64, NN / 64), 256, 0, stream>>>(mcatb, wihb, bih, gi, 2 * DD, 2 * DD, 768, 2 * DD);
    gates_ln<<<NN / 4, 256, 0, stream>>>(gi, P, x, lng, lnb, out);
}

// Round 5
// 209.153 us; speedup vs baseline: 1.9057x; 1.0354x over previous
//
#include <hip/hip_runtime.h>

#define NN 2048
#define DD 256
#define HH 4
#define PW 1280      // gemm1 output width: 256 msg0 | 256 msg1 | 768 gh
#define ECAP 128

typedef unsigned short ushort_t;
typedef __attribute__((ext_vector_type(8))) short s8;
typedef __attribute__((ext_vector_type(4))) float f4;

__device__ __forceinline__ ushort_t f2b(float f) {   // fp32 -> bf16 bits, RNE
    unsigned int u = __float_as_uint(f);
    return (ushort_t)((u + 0x7fffu + ((u >> 16) & 1u)) >> 16);
}
__device__ __forceinline__ float b2f(ushort_t b) {
    return __uint_as_float(((unsigned int)b) << 16);
}

#define NB_CONV 4885   // ceil(1250560 / 256)

// ---------------------------------------------------------------------------
// prep: blocks [0, NB_CONV): bf16-ize x, Wcat=[Wm0;Wm1;whh], wih; build bcat;
//       zero cnt.  blocks [NB_CONV, NB_CONV+128): attn projections
//       acur/anb[l][i][h] = x[i] . Wa_l[h, half]  (fp32, exact).
// ---------------------------------------------------------------------------
__global__ __launch_bounds__(256) void prep_kernel(
    const float* __restrict__ x, const float* __restrict__ Wm0, const float* __restrict__ Wm1,
    const float* __restrict__ whh, const float* __restrict__ wih,
    const float* __restrict__ bm0, const float* __restrict__ bm1, const float* __restrict__ bhh,
    const float* __restrict__ Wa0, const float* __restrict__ Wa1,
    ushort_t* __restrict__ xb, ushort_t* __restrict__ Wcatb, ushort_t* __restrict__ wihb,
    float* __restrict__ bcat, int* __restrict__ cnt,
    float* __restrict__ acur, float* __restrict__ anb)
{
    __shared__ float xs[16][257];
    const int t = threadIdx.x;
    if (blockIdx.x < NB_CONV) {
        int id = blockIdx.x * 256 + t;
        if (id < NN * DD) { xb[id] = f2b(x[id]); return; }
        id -= NN * DD;
        if (id < PW * DD) {
            const int c = id >> 8, k = id & 255;
            const float v = (c < 256) ? Wm0[c * DD + k]
                          : (c < 512) ? Wm1[(c - 256) * DD + k]
                                      : whh[(c - 512) * DD + k];
            Wcatb[id] = f2b(v); return;
        }
        id -= PW * DD;
        if (id < 768 * 512) { wihb[id] = f2b(wih[id]); return; }
        id -= 768 * 512;
        if (id < PW) {
            bcat[id] = (id < 256) ? bm0[id] : (id < 512) ? bm1[id - 256] : bhh[id - 512];
            return;
        }
        id -= PW;
        if (id < 2 * NN) cnt[id] = 0;
        return;
    }
    const int i0 = (blockIdx.x - NB_CONV) * 16;
    for (int rr = 0; rr < 16; ++rr)
        xs[rr][t] = x[(size_t)(i0 + rr) * DD + t];
    __syncthreads();
    const int r = t >> 4, idx = t & 15;
    const int l = idx >> 3, isnb = (idx >> 2) & 1, h = idx & 3;
    const float* wrow = (l ? Wa1 : Wa0) + h * (2 * DD) + isnb * DD;
    float acc = 0.f;
    for (int k = 0; k < DD; ++k) acc = fmaf(xs[r][k], wrow[k], acc);
    float* dst = isnb ? anb : acur;
    dst[((size_t)l * NN + i0 + r) * HH + h] = acc;
}

// ---------------------------------------------------------------------------
// gemm_mfma: C = A[M,K] @ B[N,K]^T + bias. A,B bf16. 64x64 tile, 4 waves of
// 2x2 mfma_f32_16x16x32_bf16. split=1 (gemm1): cols<512 -> bf16 msgb[row*512],
// cols>=512 -> fp32 gh[row*768 + col-512]. split=0: fp32 Cf[row*ldc + col].
// ---------------------------------------------------------------------------
__global__ __launch_bounds__(256) void gemm_mfma(
    const ushort_t* __restrict__ A, const ushort_t* __restrict__ B,
    const float* __restrict__ bias,
    float* __restrict__ Cf, ushort_t* __restrict__ Cb,
    int lda, int ldb, int ldc, int K, int split)
{
    __shared__ ushort_t as[64][72];
    __shared__ ushort_t bs[64][72];
    const int t = threadIdx.x;
    const int wave = t >> 6, lane = t & 63;
    const int r0 = blockIdx.y * 64, c0 = blockIdx.x * 64;
    const int wm = (wave & 1) * 32, wn = (wave >> 1) * 32;
    const int fm = lane & 15, fq = lane >> 4;

    f4 acc[2][2] = {};

    for (int k0 = 0; k0 < K; k0 += 64) {
        #pragma unroll
        for (int it = 0; it < 2; ++it) {
            const int q = t + it * 256;
            const int m = q >> 3, c = q & 7;
            *(uint4*)&as[m][c * 8] = *(const uint4*)(A + (size_t)(r0 + m) * lda + k0 + c * 8);
            *(uint4*)&bs[m][c * 8] = *(const uint4*)(B + (size_t)(c0 + m) * ldb + k0 + c * 8);
        }
        __syncthreads();
        #pragma unroll
        for (int kk = 0; kk < 2; ++kk) {
            const int kb = kk * 32 + fq * 8;
            const s8 a0 = *(const s8*)&as[wm + fm][kb];
            const s8 a1 = *(const s8*)&as[wm + 16 + fm][kb];
            const s8 b0 = *(const s8*)&bs[wn + fm][kb];
            const s8 b1 = *(const s8*)&bs[wn + 16 + fm][kb];
            acc[0][0] = __builtin_amdgcn_mfma_f32_16x16x32_bf16(a0, b0, acc[0][0], 0, 0, 0);
            acc[0][1] = __builtin_amdgcn_mfma_f32_16x16x32_bf16(a0, b1, acc[0][1], 0, 0, 0);
            acc[1][0] = __builtin_amdgcn_mfma_f32_16x16x32_bf16(a1, b0, acc[1][0], 0, 0, 0);
            acc[1][1] = __builtin_amdgcn_mfma_f32_16x16x32_bf16(a1, b1, acc[1][1], 0, 0, 0);
        }
        __syncthreads();
    }
    // C/D layout (m89-verified): col = lane&15, row = (lane>>4)*4 + reg
    #pragma unroll
    for (int ni = 0; ni < 2; ++ni) {
        const int col = c0 + wn + ni * 16 + fm;
        const float bv = bias[col];
        #pragma unroll
        for (int mi = 0; mi < 2; ++mi) {
            #pragma unroll
            for (int r = 0; r < 4; ++r) {
                const int row = r0 + wm + mi * 16 + fq * 4 + r;
                const float v = acc[mi][ni][r] + bv;
                if (!split) {
                    Cf[(size_t)row * ldc + col] = v;
                } else if (col < 512) {
                    Cb[(size_t)row * 512 + col] = f2b(v);          // msg (bf16)
                } else {
                    Cf[(size_t)row * 768 + col - 512] = v;         // gh (fp32)
                }
            }
        }
    }
}

// ---------------------------------------------------------------------------
// edge_build: coalesced scan of adj rows; scatter (j, w) into per-column lists.
// ---------------------------------------------------------------------------
__global__ __launch_bounds__(256) void edge_build(
    const float* __restrict__ adj0, const float* __restrict__ adj1,
    const float* __restrict__ w0, const float* __restrict__ w1,
    int* __restrict__ cnt, int* __restrict__ ej, float* __restrict__ ew)
{
    const int j = blockIdx.x, l = blockIdx.y, t = threadIdx.x;
    const float* adj = l ? adj1 : adj0;
    const float* w   = l ? w1 : w0;
    #pragma unroll
    for (int it = 0; it < 2; ++it) {
        const int i4 = (t + it * 256) * 4;
        const float4 a = *(const float4*)(adj + (size_t)j * NN + i4);
        const float av[4] = {a.x, a.y, a.z, a.w};
        #pragma unroll
        for (int u = 0; u < 4; ++u) {
            if (av[u] != 0.f) {
                const int i = i4 + u;
                const int slot = atomicAdd(&cnt[l * NN + i], 1);
                if (slot < ECAP) {
                    const size_t base = ((size_t)l * NN + i) * ECAP + slot;
                    ej[base] = j;
                    ew[base] = w[(size_t)j * NN + i];
                }
            }
        }
    }
}

// ---------------------------------------------------------------------------
// attn: edge-only softmax (== dense reference: exp(NEG-m) underflows to 0;
// isolated -> 0 via inv=0) + aggregation of bf16 msg rows -> bf16 mcat.
// Softmax: wave h owns head h, butterfly shfl_xor over 64 lanes (ne<=128).
// ---------------------------------------------------------------------------
__global__ __launch_bounds__(256) void attn_kernel(
    const int* __restrict__ cnt, const int* __restrict__ ej, const float* __restrict__ ew,
    const float* __restrict__ acur, const float* __restrict__ anb,
    const float* __restrict__ ba0, const float* __restrict__ ba1,
    const ushort_t* __restrict__ msgb, ushort_t* __restrict__ mcatb)
{
    const int i = blockIdx.x, l = blockIdx.y, t = threadIdx.x;
    __shared__ float es[HH][ECAP];
    __shared__ int ejs[ECAP];
    const int ne = min(cnt[l * NN + i], ECAP);
    const float* ba = l ? ba1 : ba0;
    const size_t ebase = ((size_t)l * NN + i) * ECAP;

    if (t < ne) {
        const int j = ej[ebase + t];
        const float wv = ew[ebase + t];
        ejs[t] = j;
        const float4 av = *(const float4*)(anb + ((size_t)l * NN + j) * HH);
        const float sv[4] = {av.x, av.y, av.z, av.w};
        #pragma unroll
        for (int h = 0; h < HH; ++h) {
            float s = sv[h] + acur[((size_t)l * NN + i) * HH + h] + ba[h];
            s = (s > 0.f) ? s : 0.2f * s;           // leaky_relu(0.2)
            es[h][t] = s * wv;
        }
    }
    __syncthreads();
    {
        const int h = t >> 6, lane = t & 63;
        float s0 = (lane < ne) ? es[h][lane] : -1e30f;
        float s1 = (lane + 64 < ne) ? es[h][lane + 64] : -1e30f;
        float m = fmaxf(s0, s1);
        #pragma unroll
        for (int off = 32; off; off >>= 1) m = fmaxf(m, __shfl_xor(m, off));
        const float p0 = expf(s0 - m), p1 = expf(s1 - m);
        float sum = p0 + p1;
        #pragma unroll
        for (int off = 32; off; off >>= 1) sum += __shfl_xor(sum, off);
        const float inv = (ne > 0) ? 1.f / sum : 0.f;
        es[h][lane] = p0 * inv;
        if (lane + 64 < ECAP) es[h][lane + 64] = p1 * inv;
    }
    __syncthreads();
    const int h = t >> 6;
    float acc = 0.f;
    for (int e = 0; e < ne; ++e)
        acc = fmaf(es[h][e], b2f(msgb[(size_t)ejs[e] * 512 + l * DD + t]), acc);
    mcatb[(size_t)i * (2 * DD) + l * DD + t] = f2b(acc);
}

// ---------------------------------------------------------------------------
// gates_ln: GRU gates (gi includes bih via gemm bias) + LayerNorm.
// ---------------------------------------------------------------------------
__global__ __launch_bounds__(256) void gates_ln(
    const float* __restrict__ gi, const float* __restrict__ gh, const float* __restrict__ x,
    const float* __restrict__ lng, const float* __restrict__ lnb, float* __restrict__ out)
{
    __shared__ float rs1[4], rs2[4];
    const int t = threadIdx.x;
    const int r0 = blockIdx.x * 4;
    const float gv = lng[t], bv = lnb[t];
    float hv[4];
    #pragma unroll
    for (int r = 0; r < 4; ++r) {
        const int row = r0 + r;
        const float gir = gi[(size_t)row * 768 + t];
        const float giz = gi[(size_t)row * 768 + 256 + t];
        const float gin = gi[(size_t)row * 768 + 512 + t];
        const float ghr = gh[(size_t)row * 768 + t];
        const float ghz = gh[(size_t)row * 768 + 256 + t];
        const float ghn = gh[(size_t)row * 768 + 512 + t];
        const float rr = 1.f / (1.f + expf(-(gir + ghr)));
        const float zz = 1.f / (1.f + expf(-(giz + ghz)));
        const float nn = tanhf(gin + rr * ghn);
        hv[r] = (1.f - zz) * nn + zz * x[(size_t)row * DD + t];
    }
    const int lane = t & 63, wid = t >> 6;
    for (int r = 0; r < 4; ++r) {
        float s1 = hv[r], s2 = hv[r] * hv[r];
        #pragma unroll
        for (int off = 32; off; off >>= 1) {
            s1 += __shfl_down(s1, off);
            s2 += __shfl_down(s2, off);
        }
        if (lane == 0) { rs1[wid] = s1; rs2[wid] = s2; }
        __syncthreads();
        const float sum = rs1[0] + rs1[1] + rs1[2] + rs1[3];
        const float sq  = rs2[0] + rs2[1] + rs2[2] + rs2[3];
        const float mu  = sum * (1.f / DD);
        const float var = sq * (1.f / DD) - mu * mu;
        const float inv = rsqrtf(var + 1e-5f);
        out[(size_t)(r0 + r) * DD + t] = (hv[r] - mu) * inv * gv + bv;
        __syncthreads();
    }
}

extern "C" void kernel_launch(void* const* d_in, const int* in_sizes, int n_in,
                              void* d_out, int out_size, void* d_ws, size_t ws_size,
                              hipStream_t stream)
{
    const float* x    = (const float*)d_in[0];
    const float* adj0 = (const float*)d_in[1];
    const float* adj1 = (const float*)d_in[2];
    const float* w0   = (const float*)d_in[3];
    const float* w1   = (const float*)d_in[4];
    const float* Wm0  = (const float*)d_in[5];
    const float* bm0  = (const float*)d_in[6];
    const float* Wa0  = (const float*)d_in[7];
    const float* ba0  = (const float*)d_in[8];
    const float* Wm1  = (const float*)d_in[9];
    const float* bm1  = (const float*)d_in[10];
    const float* Wa1  = (const float*)d_in[11];
    const float* ba1  = (const float*)d_in[12];
    const float* wih  = (const float*)d_in[13];
    const float* whh  = (const float*)d_in[14];
    const float* bih  = (const float*)d_in[15];
    const float* bhh  = (const float*)d_in[16];
    const float* lng  = (const float*)d_in[17];
    const float* lnb  = (const float*)d_in[18];
    float* out = (float*)d_out;

    float* ws = (float*)d_ws;
    float* gh   = ws;            ws += (size_t)NN * 768;  // fp32
    float* gi   = ws;            ws += (size_t)NN * 768;  // fp32
    float* bcat = ws;            ws += PW;
    float* acur = ws;            ws += 2 * NN * HH;
    float* anb  = ws;            ws += 2 * NN * HH;
    int*   cnt  = (int*)ws;      ws += 2 * NN;
    int*   ej   = (int*)ws;      ws += 2 * NN * ECAP;
    float* ew   = ws;            ws += 2 * NN * ECAP;
    ushort_t* xb    = (ushort_t*)ws;  ws += (size_t)NN * DD / 2;
    ushort_t* Wcatb = (ushort_t*)ws;  ws += (size_t)PW * DD / 2;
    ushort_t* wihb  = (ushort_t*)ws;  ws += (size_t)768 * 512 / 2;
    ushort_t* msgb  = (ushort_t*)ws;  ws += (size_t)NN * 512 / 2;
    ushort_t* mcatb = (ushort_t*)ws;  ws += (size_t)NN * 512 / 2;
    // total ~22 MB

    prep_kernel<<<NB_CONV + NN / 16, 256, 0, stream>>>(
        x, Wm0, Wm1, whh, wih, bm0, bm1, bhh, Wa0, Wa1,
        xb, Wcatb, wihb, bcat, cnt, acur, anb);
    gemm_mfma<<<dim3(PW / 64, NN / 64), 256, 0, stream>>>(
        xb, Wcatb, bcat, gh, msgb, DD, DD, 0, DD, 1);
    edge_build<<<dim3(NN, 2), 256, 0, stream>>>(adj0, adj1, w0, w1, cnt, ej, ew);
    attn_kernel<<<dim3(NN, 2), 256, 0, stream>>>(cnt, ej, ew, acur, anb, ba0, ba1, msgb, mcatb);
    gemm_mfma<<<dim3(768 / 64, NN / 64), 256, 0, stream>>>(
        mcatb, wihb, bih, gi, (ushort_t*)nullptr, 2 * DD, 2 * DD, 768, 2 * DD, 0);
    gates_ln<<<NN / 4, 256, 0, stream>>>(gi, gh, x, lng, lnb, out);
}

// Round 6
// 200.257 us; speedup vs baseline: 1.9904x; 1.0444x over previous
//
#include <hip/hip_runtime.h>

#define NN 2048
#define DD 256
#define HH 4
#define PW 1280      // gemm1 output width: 256 msg0 | 256 msg1 | 768 gh
#define ECAP 128

typedef unsigned short ushort_t;
typedef __attribute__((ext_vector_type(8))) short s8;
typedef __attribute__((ext_vector_type(4))) float f4;

__device__ __forceinline__ ushort_t f2b(float f) {   // fp32 -> bf16 bits, RNE
    unsigned int u = __float_as_uint(f);
    return (ushort_t)((u + 0x7fffu + ((u >> 16) & 1u)) >> 16);
}
__device__ __forceinline__ float b2f(ushort_t b) {
    return __uint_as_float(((unsigned int)b) << 16);
}
__device__ __forceinline__ void gl_lds16(const void* g, void* l) {
    __builtin_amdgcn_global_load_lds(
        (const __attribute__((address_space(1))) void*)g,
        (__attribute__((address_space(3))) void*)l, 16, 0, 0);
}

#define NB_CONV 4885   // ceil(1250560 / 256)

// ---------------------------------------------------------------------------
// prep: blocks [0, NB_CONV): bf16-ize x, Wcat=[Wm0;Wm1;whh], wih; build bcat;
//       zero cnt.  blocks [NB_CONV, NB_CONV+128): attn projections
//       acur/anb[l][i][h] = x[i] . Wa_l[h, half]  (fp32, exact).
// ---------------------------------------------------------------------------
__global__ __launch_bounds__(256) void prep_kernel(
    const float* __restrict__ x, const float* __restrict__ Wm0, const float* __restrict__ Wm1,
    const float* __restrict__ whh, const float* __restrict__ wih,
    const float* __restrict__ bm0, const float* __restrict__ bm1, const float* __restrict__ bhh,
    const float* __restrict__ Wa0, const float* __restrict__ Wa1,
    ushort_t* __restrict__ xb, ushort_t* __restrict__ Wcatb, ushort_t* __restrict__ wihb,
    float* __restrict__ bcat, int* __restrict__ cnt,
    float* __restrict__ acur, float* __restrict__ anb)
{
    __shared__ float xs[16][257];
    const int t = threadIdx.x;
    if (blockIdx.x < NB_CONV) {
        int id = blockIdx.x * 256 + t;
        if (id < NN * DD) { xb[id] = f2b(x[id]); return; }
        id -= NN * DD;
        if (id < PW * DD) {
            const int c = id >> 8, k = id & 255;
            const float v = (c < 256) ? Wm0[c * DD + k]
                          : (c < 512) ? Wm1[(c - 256) * DD + k]
                                      : whh[(c - 512) * DD + k];
            Wcatb[id] = f2b(v); return;
        }
        id -= PW * DD;
        if (id < 768 * 512) { wihb[id] = f2b(wih[id]); return; }
        id -= 768 * 512;
        if (id < PW) {
            bcat[id] = (id < 256) ? bm0[id] : (id < 512) ? bm1[id - 256] : bhh[id - 512];
            return;
        }
        id -= PW;
        if (id < 2 * NN) cnt[id] = 0;
        return;
    }
    const int i0 = (blockIdx.x - NB_CONV) * 16;
    for (int rr = 0; rr < 16; ++rr)
        xs[rr][t] = x[(size_t)(i0 + rr) * DD + t];
    __syncthreads();
    const int r = t >> 4, idx = t & 15;
    const int l = idx >> 3, isnb = (idx >> 2) & 1, h = idx & 3;
    const float* wrow = (l ? Wa1 : Wa0) + h * (2 * DD) + isnb * DD;
    float acc = 0.f;
    for (int k = 0; k < DD; ++k) acc = fmaf(xs[r][k], wrow[k], acc);
    float* dst = isnb ? anb : acur;
    dst[((size_t)l * NN + i0 + r) * HH + h] = acc;
}

// ---------------------------------------------------------------------------
// gemm_mfma: C = A[M,K] @ B[N,K]^T + bias. A,B bf16. 64x64 tile, 4 waves of
// 2x2 mfma_f32_16x16x32_bf16. Staging via global_load_lds (16B, async,
// wave-uniform LDS base + lane*16) into UNPADDED [64][64] with XOR swizzle
// chunk' = chunk ^ (row&7): staging is linear in lane order (legal), frag
// ds_read_b128 hits 8 distinct bank groups / 16 rows = free 2-way aliasing.
// split=1 (gemm1): cols<512 -> bf16 msgb[row*512], cols>=512 -> fp32
// gh[row*768+col-512]. split=0: fp32 Cf[row*ldc+col].
// ---------------------------------------------------------------------------
__global__ __launch_bounds__(256) void gemm_mfma(
    const ushort_t* __restrict__ A, const ushort_t* __restrict__ B,
    const float* __restrict__ bias,
    float* __restrict__ Cf, ushort_t* __restrict__ Cb,
    int lda, int ldb, int ldc, int K, int split)
{
    __shared__ ushort_t as[64][64];
    __shared__ ushort_t bs[64][64];
    const int t = threadIdx.x;
    const int wave = t >> 6, lane = t & 63;
    const int r0 = blockIdx.y * 64, c0 = blockIdx.x * 64;
    const int wm = (wave & 1) * 32, wn = (wave >> 1) * 32;
    const int fm = lane & 15, fq = lane >> 4;

    // staging geometry: wave w, sub-chunk q in {0,1}: 8 rows of 64 ushorts.
    // lane -> row m = w*16 + q*8 + (lane>>3), chunk c = lane&7,
    // global chunk c' = c ^ (m&7)  (the XOR swizzle lives in the global addr)
    const int m0q0 = wave * 16 + (lane >> 3);
    const int m0q1 = m0q0 + 8;
    const int cs0 = ((lane & 7) ^ (m0q0 & 7)) * 8;
    const int cs1 = ((lane & 7) ^ (m0q1 & 7)) * 8;
    const ushort_t* ga0 = A + (size_t)(r0 + m0q0) * lda + cs0;
    const ushort_t* ga1 = A + (size_t)(r0 + m0q1) * lda + cs1;
    const ushort_t* gb0 = B + (size_t)(c0 + m0q0) * ldb + cs0;
    const ushort_t* gb1 = B + (size_t)(c0 + m0q1) * ldb + cs1;
    ushort_t* la0 = &as[wave * 16][0];
    ushort_t* la1 = &as[wave * 16 + 8][0];
    ushort_t* lb0 = &bs[wave * 16][0];
    ushort_t* lb1 = &bs[wave * 16 + 8][0];

    // fragment row swizzle constants
    const int ra0 = wm + fm, ra1 = wm + 16 + fm;
    const int rb0 = wn + fm, rb1 = wn + 16 + fm;

    f4 acc[2][2] = {};

    for (int k0 = 0; k0 < K; k0 += 64) {
        __syncthreads();                       // prev compute done, LDS free
        gl_lds16(ga0 + k0, la0);
        gl_lds16(ga1 + k0, la1);
        gl_lds16(gb0 + k0, lb0);
        gl_lds16(gb1 + k0, lb1);
        __syncthreads();                       // drains vmcnt -> LDS visible
        #pragma unroll
        for (int kk = 0; kk < 2; ++kk) {
            const int cc = kk * 4 + fq;        // chunk index within 64-k slab
            const s8 a0 = *(const s8*)&as[ra0][(cc ^ (ra0 & 7)) * 8];
            const s8 a1 = *(const s8*)&as[ra1][(cc ^ (ra1 & 7)) * 8];
            const s8 b0 = *(const s8*)&bs[rb0][(cc ^ (rb0 & 7)) * 8];
            const s8 b1 = *(const s8*)&bs[rb1][(cc ^ (rb1 & 7)) * 8];
            acc[0][0] = __builtin_amdgcn_mfma_f32_16x16x32_bf16(a0, b0, acc[0][0], 0, 0, 0);
            acc[0][1] = __builtin_amdgcn_mfma_f32_16x16x32_bf16(a0, b1, acc[0][1], 0, 0, 0);
            acc[1][0] = __builtin_amdgcn_mfma_f32_16x16x32_bf16(a1, b0, acc[1][0], 0, 0, 0);
            acc[1][1] = __builtin_amdgcn_mfma_f32_16x16x32_bf16(a1, b1, acc[1][1], 0, 0, 0);
        }
    }
    // C/D layout (m89-verified): col = lane&15, row = (lane>>4)*4 + reg
    #pragma unroll
    for (int ni = 0; ni < 2; ++ni) {
        const int col = c0 + wn + ni * 16 + fm;
        const float bv = bias[col];
        #pragma unroll
        for (int mi = 0; mi < 2; ++mi) {
            #pragma unroll
            for (int r = 0; r < 4; ++r) {
                const int row = r0 + wm + mi * 16 + fq * 4 + r;
                const float v = acc[mi][ni][r] + bv;
                if (!split) {
                    Cf[(size_t)row * ldc + col] = v;
                } else if (col < 512) {
                    Cb[(size_t)row * 512 + col] = f2b(v);          // msg (bf16)
                } else {
                    Cf[(size_t)row * 768 + col - 512] = v;         // gh (fp32)
                }
            }
        }
    }
}

// ---------------------------------------------------------------------------
// edge_build: coalesced scan of adj rows; scatter (j, w) into per-column lists.
// ---------------------------------------------------------------------------
__global__ __launch_bounds__(256) void edge_build(
    const float* __restrict__ adj0, const float* __restrict__ adj1,
    const float* __restrict__ w0, const float* __restrict__ w1,
    int* __restrict__ cnt, int* __restrict__ ej, float* __restrict__ ew)
{
    const int j = blockIdx.x, l = blockIdx.y, t = threadIdx.x;
    const float* adj = l ? adj1 : adj0;
    const float* w   = l ? w1 : w0;
    #pragma unroll
    for (int it = 0; it < 2; ++it) {
        const int i4 = (t + it * 256) * 4;
        const float4 a = *(const float4*)(adj + (size_t)j * NN + i4);
        const float av[4] = {a.x, a.y, a.z, a.w};
        #pragma unroll
        for (int u = 0; u < 4; ++u) {
            if (av[u] != 0.f) {
                const int i = i4 + u;
                const int slot = atomicAdd(&cnt[l * NN + i], 1);
                if (slot < ECAP) {
                    const size_t base = ((size_t)l * NN + i) * ECAP + slot;
                    ej[base] = j;
                    ew[base] = w[(size_t)j * NN + i];
                }
            }
        }
    }
}

// ---------------------------------------------------------------------------
// attn: edge-only softmax (== dense reference: exp(NEG-m) underflows to 0;
// isolated -> 0 via inv=0) + aggregation of bf16 msg rows -> bf16 mcat.
// Softmax: wave h owns head h, butterfly shfl_xor. Aggregation unrolled x4
// so 4 independent gathers issue per waitcnt.
// ---------------------------------------------------------------------------
__global__ __launch_bounds__(256) void attn_kernel(
    const int* __restrict__ cnt, const int* __restrict__ ej, const float* __restrict__ ew,
    const float* __restrict__ acur, const float* __restrict__ anb,
    const float* __restrict__ ba0, const float* __restrict__ ba1,
    const ushort_t* __restrict__ msgb, ushort_t* __restrict__ mcatb)
{
    const int i = blockIdx.x, l = blockIdx.y, t = threadIdx.x;
    __shared__ float es[HH][ECAP];
    __shared__ int ejs[ECAP];
    const int ne = min(cnt[l * NN + i], ECAP);
    const float* ba = l ? ba1 : ba0;
    const size_t ebase = ((size_t)l * NN + i) * ECAP;

    if (t < ne) {
        const int j = ej[ebase + t];
        const float wv = ew[ebase + t];
        ejs[t] = j;
        const float4 av = *(const float4*)(anb + ((size_t)l * NN + j) * HH);
        const float sv[4] = {av.x, av.y, av.z, av.w};
        #pragma unroll
        for (int h = 0; h < HH; ++h) {
            float s = sv[h] + acur[((size_t)l * NN + i) * HH + h] + ba[h];
            s = (s > 0.f) ? s : 0.2f * s;           // leaky_relu(0.2)
            es[h][t] = s * wv;
        }
    }
    __syncthreads();
    {
        const int h = t >> 6, lane = t & 63;
        float s0 = (lane < ne) ? es[h][lane] : -1e30f;
        float s1 = (lane + 64 < ne) ? es[h][lane + 64] : -1e30f;
        float m = fmaxf(s0, s1);
        #pragma unroll
        for (int off = 32; off; off >>= 1) m = fmaxf(m, __shfl_xor(m, off));
        const float p0 = expf(s0 - m), p1 = expf(s1 - m);
        float sum = p0 + p1;
        #pragma unroll
        for (int off = 32; off; off >>= 1) sum += __shfl_xor(sum, off);
        const float inv = (ne > 0) ? 1.f / sum : 0.f;
        es[h][lane] = p0 * inv;
        if (lane + 64 < ECAP) es[h][lane + 64] = p1 * inv;
    }
    __syncthreads();
    const int h = t >> 6;
    const int off = l * DD + t;
    float acc = 0.f;
    int e = 0;
    for (; e + 4 <= ne; e += 4) {
        const float v0 = b2f(msgb[(size_t)ejs[e + 0] * 512 + off]);
        const float v1 = b2f(msgb[(size_t)ejs[e + 1] * 512 + off]);
        const float v2 = b2f(msgb[(size_t)ejs[e + 2] * 512 + off]);
        const float v3 = b2f(msgb[(size_t)ejs[e + 3] * 512 + off]);
        acc = fmaf(es[h][e + 0], v0, acc);
        acc = fmaf(es[h][e + 1], v1, acc);
        acc = fmaf(es[h][e + 2], v2, acc);
        acc = fmaf(es[h][e + 3], v3, acc);
    }
    for (; e < ne; ++e)
        acc = fmaf(es[h][e], b2f(msgb[(size_t)ejs[e] * 512 + off]), acc);
    mcatb[(size_t)i * (2 * DD) + off] = f2b(acc);
}

// ---------------------------------------------------------------------------
// gates_ln: GRU gates (gi includes bih via gemm bias) + LayerNorm.
// ---------------------------------------------------------------------------
__global__ __launch_bounds__(256) void gates_ln(
    const float* __restrict__ gi, const float* __restrict__ gh, const float* __restrict__ x,
    const float* __restrict__ lng, const float* __restrict__ lnb, float* __restrict__ out)
{
    __shared__ float rs1[4], rs2[4];
    const int t = threadIdx.x;
    const int r0 = blockIdx.x * 4;
    const float gv = lng[t], bv = lnb[t];
    float hv[4];
    #pragma unroll
    for (int r = 0; r < 4; ++r) {
        const int row = r0 + r;
        const float gir = gi[(size_t)row * 768 + t];
        const float giz = gi[(size_t)row * 768 + 256 + t];
        const float gin = gi[(size_t)row * 768 + 512 + t];
        const float ghr = gh[(size_t)row * 768 + t];
        const float ghz = gh[(size_t)row * 768 + 256 + t];
        const float ghn = gh[(size_t)row * 768 + 512 + t];
        const float rr = 1.f / (1.f + expf(-(gir + ghr)));
        const float zz = 1.f / (1.f + expf(-(giz + ghz)));
        const float nn = tanhf(gin + rr * ghn);
        hv[r] = (1.f - zz) * nn + zz * x[(size_t)row * DD + t];
    }
    const int lane = t & 63, wid = t >> 6;
    for (int r = 0; r < 4; ++r) {
        float s1 = hv[r], s2 = hv[r] * hv[r];
        #pragma unroll
        for (int off = 32; off; off >>= 1) {
            s1 += __shfl_down(s1, off);
            s2 += __shfl_down(s2, off);
        }
        if (lane == 0) { rs1[wid] = s1; rs2[wid] = s2; }
        __syncthreads();
        const float sum = rs1[0] + rs1[1] + rs1[2] + rs1[3];
        const float sq  = rs2[0] + rs2[1] + rs2[2] + rs2[3];
        const float mu  = sum * (1.f / DD);
        const float var = sq * (1.f / DD) - mu * mu;
        const float inv = rsqrtf(var + 1e-5f);
        out[(size_t)(r0 + r) * DD + t] = (hv[r] - mu) * inv * gv + bv;
        __syncthreads();
    }
}

extern "C" void kernel_launch(void* const* d_in, const int* in_sizes, int n_in,
                              void* d_out, int out_size, void* d_ws, size_t ws_size,
                              hipStream_t stream)
{
    const float* x    = (const float*)d_in[0];
    const float* adj0 = (const float*)d_in[1];
    const float* adj1 = (const float*)d_in[2];
    const float* w0   = (const float*)d_in[3];
    const float* w1   = (const float*)d_in[4];
    const float* Wm0  = (const float*)d_in[5];
    const float* bm0  = (const float*)d_in[6];
    const float* Wa0  = (const float*)d_in[7];
    const float* ba0  = (const float*)d_in[8];
    const float* Wm1  = (const float*)d_in[9];
    const float* bm1  = (const float*)d_in[10];
    const float* Wa1  = (const float*)d_in[11];
    const float* ba1  = (const float*)d_in[12];
    const float* wih  = (const float*)d_in[13];
    const float* whh  = (const float*)d_in[14];
    const float* bih  = (const float*)d_in[15];
    const float* bhh  = (const float*)d_in[16];
    const float* lng  = (const float*)d_in[17];
    const float* lnb  = (const float*)d_in[18];
    float* out = (float*)d_out;

    float* ws = (float*)d_ws;
    float* gh   = ws;            ws += (size_t)NN * 768;  // fp32
    float* gi   = ws;            ws += (size_t)NN * 768;  // fp32
    float* bcat = ws;            ws += PW;
    float* acur = ws;            ws += 2 * NN * HH;
    float* anb  = ws;            ws += 2 * NN * HH;
    int*   cnt  = (int*)ws;      ws += 2 * NN;
    int*   ej   = (int*)ws;      ws += 2 * NN * ECAP;
    float* ew   = ws;            ws += 2 * NN * ECAP;
    ushort_t* xb    = (ushort_t*)ws;  ws += (size_t)NN * DD / 2;
    ushort_t* Wcatb = (ushort_t*)ws;  ws += (size_t)PW * DD / 2;
    ushort_t* wihb  = (ushort_t*)ws;  ws += (size_t)768 * 512 / 2;
    ushort_t* msgb  = (ushort_t*)ws;  ws += (size_t)NN * 512 / 2;
    ushort_t* mcatb = (ushort_t*)ws;  ws += (size_t)NN * 512 / 2;
    // total ~22 MB

    prep_kernel<<<NB_CONV + NN / 16, 256, 0, stream>>>(
        x, Wm0, Wm1, whh, wih, bm0, bm1, bhh, Wa0, Wa1,
        xb, Wcatb, wihb, bcat, cnt, acur, anb);
    gemm_mfma<<<dim3(PW / 64, NN / 64), 256, 0, stream>>>(
        xb, Wcatb, bcat, gh, msgb, DD, DD, 0, DD, 1);
    edge_build<<<dim3(NN, 2), 256, 0, stream>>>(adj0, adj1, w0, w1, cnt, ej, ew);
    attn_kernel<<<dim3(NN, 2), 256, 0, stream>>>(cnt, ej, ew, acur, anb, ba0, ba1, msgb, mcatb);
    gemm_mfma<<<dim3(768 / 64, NN / 64), 256, 0, stream>>>(
        mcatb, wihb, bih, gi, (ushort_t*)nullptr, 2 * DD, 2 * DD, 768, 2 * DD, 0);
    gates_ln<<<NN / 4, 256, 0, stream>>>(gi, gh, x, lng, lnb, out);
}